// Round 1
// baseline (76.567 us; speedup 1.0000x reference)
//
#include <hip/hip_runtime.h>

#define NN 4096
#define CHUNK 128

// ---------------------------------------------------------------------------
// Kernel A: pairwise repulsion forces, j-split across grid.y for occupancy.
//   rep[i] += sum_{j in chunk} 10*exp((0.6-d)/0.71) * (pos_i-pos_j)/d
// d = sqrt(dx^2+dy^2+1e-8). Diagonal contributes exactly 0 (dx=dy=0), no mask.
// Constants folded: 10*exp(u) = exp(u + ln10);
//   arg = (0.6-d)/0.71 + ln10 = fma(-1/0.71, d, 0.6/0.71 + ln10)
// ---------------------------------------------------------------------------
__global__ __launch_bounds__(256) void rep_forces(const float* __restrict__ state,
                                                  float* __restrict__ rep) {
    __shared__ float2 sp[CHUNK];
    const int i = blockIdx.x * 256 + threadIdx.x;
    const int jbase = blockIdx.y * CHUNK;
    if (threadIdx.x < CHUNK) {
        float4 s = reinterpret_cast<const float4*>(state)[jbase + threadIdx.x];
        sp[threadIdx.x] = make_float2(s.x, s.y);
    }
    __syncthreads();

    const float4 me = reinterpret_cast<const float4*>(state)[i];
    const float px = me.x, py = me.y;
    float fx = 0.f, fy = 0.f;

    const float C1 = 1.40845070422535f;   // 1/0.71
    const float C0 = 3.14765551813f;      // 0.6/0.71 + ln(10)

#pragma unroll 8
    for (int t = 0; t < CHUNK; ++t) {
        float2 q = sp[t];                  // lane-uniform LDS broadcast
        float dx = px - q.x;
        float dy = py - q.y;
        float d2 = fmaf(dx, dx, 1e-8f);
        d2 = fmaf(dy, dy, d2);
        float inv_d = rsqrtf(d2);          // v_rsq_f32
        float d = d2 * inv_d;              // = sqrt(d2)
        float e = __expf(fmaf(-C1, d, C0)); // v_exp_f32, includes *10
        float w = e * inv_d;
        fx = fmaf(w, dx, fx);
        fy = fmaf(w, dy, fy);
    }
    atomicAdd(&rep[2 * i],     fx);
    atomicAdd(&rep[2 * i + 1], fy);
}

// ---------------------------------------------------------------------------
// Kernel B: attraction force + pose propagation. Also writes the second half
// of `stacked` (a copy of the input state).
// attr = 2*(1.5*e_goal - vel)*60 = 180*e_goal - 120*vel
// ---------------------------------------------------------------------------
__global__ __launch_bounds__(256) void propagate(const float* __restrict__ state,
                                                 const float* __restrict__ goals,
                                                 const float* __restrict__ rep,
                                                 float* __restrict__ out_state,
                                                 float* __restrict__ stacked_second) {
    const int i = blockIdx.x * 256 + threadIdx.x;
    const float4 me = reinterpret_cast<const float4*>(state)[i];
    const float2 g  = reinterpret_cast<const float2*>(goals)[i];

    float tgx = g.x - me.x, tgy = g.y - me.y;
    float dist = sqrtf(tgx * tgx + tgy * tgy);
    float inv = 1.f / (dist + 1e-8f);
    float Fx = rep[2 * i]     + 180.f * (tgx * inv) - 120.f * me.z;
    float Fy = rep[2 * i + 1] + 180.f * (tgy * inv) - 120.f * me.w;

    float vnx = me.z + Fx * (0.4f / 60.f);
    float vny = me.w + Fy * (0.4f / 60.f);
    float speed = sqrtf(vnx * vnx + vny * vny);
    float scale = fminf(1.f, 1.5f / (speed + 1e-8f));
    vnx *= scale;
    vny *= scale;
    float pnx = me.x + vnx * 0.4f;
    float pny = me.y + vny * 0.4f;

    reinterpret_cast<float4*>(out_state)[i]      = make_float4(pnx, pny, vnx, vny);
    reinterpret_cast<float4*>(stacked_second)[i] = me;  // stacked[N:2N] = state
}

// ---------------------------------------------------------------------------
// Kernel C: cost function (needs pos_new[0] -> separate dispatch after B).
// Also writes the first half of `stacked` (copy of visualizer input).
// ---------------------------------------------------------------------------
__global__ __launch_bounds__(256) void cost_and_copy(const float* __restrict__ out_state,
                                                     const float* __restrict__ cost_in,
                                                     const float* __restrict__ goals,
                                                     const float* __restrict__ robot_init,
                                                     const float* __restrict__ stacked_in,
                                                     float* __restrict__ cost_out,
                                                     float* __restrict__ stacked_first) {
    const int i = blockIdx.x * 256 + threadIdx.x;

    float rx = out_state[0], ry = out_state[1];    // broadcast loads
    float r0x = robot_init[0], r0y = robot_init[1];
    float gdx = goals[0] - r0x, gdy = goals[1] - r0y;
    float PG = (gdx * (rx - r0x) + gdy * (ry - r0y))
             / (sqrtf(gdx * gdx + gdy * gdy) + 0.001f);

    float px = out_state[4 * i], py = out_state[4 * i + 1];
    float ddx = px - rx, ddy = py - ry;
    float dist = sqrtf(ddx * ddx + ddy * ddy + 0.001f);
    float blame = (i == 0) ? 0.f : __expf(-dist * (1.f / 1.2f));

    cost_out[i] = cost_in[i] + (-4.f * PG + blame);
    reinterpret_cast<float4*>(stacked_first)[i] =
        reinterpret_cast<const float4*>(stacked_in)[i];  // stacked[0:N]
}

extern "C" void kernel_launch(void* const* d_in, const int* in_sizes, int n_in,
                              void* d_out, int out_size, void* d_ws, size_t ws_size,
                              hipStream_t stream) {
    const float* state      = (const float*)d_in[0];   // (N,4)
    const float* cost       = (const float*)d_in[1];   // (N,1)
    const float* stacked_in = (const float*)d_in[2];   // (N,4)
    const float* goals      = (const float*)d_in[3];   // (N,2)
    const float* robot_init = (const float*)d_in[4];   // (2,)

    float* out          = (float*)d_out;
    float* out_state    = out;               // N*4 = 16384
    float* out_cost     = out + NN * 4;      // N   =  4096
    float* out_stacked  = out + NN * 5;      // 2N*4 = 32768

    float* rep = (float*)d_ws;               // N*2 floats of scratch (32 KB)

    hipMemsetAsync(rep, 0, NN * 2 * sizeof(float), stream);

    dim3 gridA(NN / 256, NN / CHUNK);        // 16 x 32 = 512 blocks
    rep_forces<<<gridA, 256, 0, stream>>>(state, rep);

    propagate<<<NN / 256, 256, 0, stream>>>(state, goals, rep,
                                            out_state, out_stacked + NN * 4);

    cost_and_copy<<<NN / 256, 256, 0, stream>>>(out_state, cost, goals, robot_init,
                                                stacked_in, out_cost, out_stacked);
}

// Round 2
// 72.379 us; speedup vs baseline: 1.0579x; 1.0579x over previous
//
#include <hip/hip_runtime.h>

#define NN 4096
#define CHUNK 64
#define NCHUNK (NN / CHUNK)   // 64 j-chunks -> grid 16x64 = 1024 blocks (4/CU)

// ---------------------------------------------------------------------------
// Kernel A: pairwise repulsion partial sums. Block (bx,by) computes, for its
// 256 i's, the sum over j in [by*64, by*64+64) of
//   10*exp((0.6-d)/0.71) * (pos_i-pos_j)/d ,  d = sqrt(dx^2+dy^2+1e-8)
// Diagonal contributes exactly 0 (dx=dy=0 -> w*dx = 0), no mask needed.
// Constants pre-scaled by log2(e) so the native v_exp_f32 (exp2) does it all:
//   10*exp((0.6-d)/0.71) = exp2(C0E - C1E*d)
//   C1E = log2(e)/0.71            = 2.0319648462
//   C0E = (0.6/0.71 + ln10)*log2e = 4.5411071
// Partials go to ws (no atomics, no memset); reduced in `propagate`.
// ---------------------------------------------------------------------------
__global__ __launch_bounds__(256) void rep_partial(const float* __restrict__ state,
                                                   float2* __restrict__ part) {
    __shared__ float2 sp[CHUNK];
    const int i = blockIdx.x * 256 + threadIdx.x;
    const int jbase = blockIdx.y * CHUNK;
    if (threadIdx.x < CHUNK) {
        float4 s = reinterpret_cast<const float4*>(state)[jbase + threadIdx.x];
        sp[threadIdx.x] = make_float2(s.x, s.y);
    }
    __syncthreads();

    const float4 me = reinterpret_cast<const float4*>(state)[i];
    const float px = me.x, py = me.y;
    float fx = 0.f, fy = 0.f;

    const float C1E = 2.0319648462f;
    const float C0E = 4.5411071f;

#pragma unroll 16
    for (int t = 0; t < CHUNK; ++t) {
        float2 q = sp[t];                          // lane-uniform broadcast
        float dx = px - q.x;
        float dy = py - q.y;
        float d2 = fmaf(dx, dx, 1e-8f);
        d2 = fmaf(dy, dy, d2);
        float inv_d = __builtin_amdgcn_rsqf(d2);   // v_rsq_f32
        float d = d2 * inv_d;                      // sqrt(d2)
        float e = __builtin_amdgcn_exp2f(fmaf(-C1E, d, C0E)); // v_exp_f32
        float w = e * inv_d;
        fx = fmaf(w, dx, fx);
        fy = fmaf(w, dy, fy);
    }
    part[blockIdx.y * NN + i] = make_float2(fx, fy);  // coalesced, no atomics
}

// ---------------------------------------------------------------------------
// Kernel B: reduce partials + attraction force + pose propagation.
// Also writes stacked[N:2N] (copy of input state).
// attr = 2*(1.5*e_goal - vel)*60 = 180*e_goal - 120*vel
// ---------------------------------------------------------------------------
__global__ __launch_bounds__(256) void propagate(const float* __restrict__ state,
                                                 const float* __restrict__ goals,
                                                 const float2* __restrict__ part,
                                                 float* __restrict__ out_state,
                                                 float* __restrict__ stacked_second) {
    const int i = blockIdx.x * 256 + threadIdx.x;

    float Fx = 0.f, Fy = 0.f;
#pragma unroll
    for (int c = 0; c < NCHUNK; ++c) {            // coalesced float2 loads
        float2 p = part[c * NN + i];
        Fx += p.x;
        Fy += p.y;
    }

    const float4 me = reinterpret_cast<const float4*>(state)[i];
    const float2 g  = reinterpret_cast<const float2*>(goals)[i];

    float tgx = g.x - me.x, tgy = g.y - me.y;
    float dist = sqrtf(tgx * tgx + tgy * tgy);
    float inv = 1.f / (dist + 1e-8f);
    Fx += 180.f * (tgx * inv) - 120.f * me.z;
    Fy += 180.f * (tgy * inv) - 120.f * me.w;

    float vnx = me.z + Fx * (0.4f / 60.f);
    float vny = me.w + Fy * (0.4f / 60.f);
    float speed = sqrtf(vnx * vnx + vny * vny);
    float scale = fminf(1.f, 1.5f / (speed + 1e-8f));
    vnx *= scale;
    vny *= scale;
    float pnx = me.x + vnx * 0.4f;
    float pny = me.y + vny * 0.4f;

    reinterpret_cast<float4*>(out_state)[i]      = make_float4(pnx, pny, vnx, vny);
    reinterpret_cast<float4*>(stacked_second)[i] = me;   // stacked[N:2N] = state
}

// ---------------------------------------------------------------------------
// Kernel C: cost (needs pos_new[0] -> must follow B). Writes stacked[0:N].
// exp(-dist/1.2) = exp2(-dist * log2(e)/1.2) = exp2(-0.8333*1.442695*dist)
// ---------------------------------------------------------------------------
__global__ __launch_bounds__(256) void cost_and_copy(const float* __restrict__ out_state,
                                                     const float* __restrict__ cost_in,
                                                     const float* __restrict__ goals,
                                                     const float* __restrict__ robot_init,
                                                     const float* __restrict__ stacked_in,
                                                     float* __restrict__ cost_out,
                                                     float* __restrict__ stacked_first) {
    const int i = blockIdx.x * 256 + threadIdx.x;

    float rx = out_state[0], ry = out_state[1];    // broadcast loads
    float r0x = robot_init[0], r0y = robot_init[1];
    float gdx = goals[0] - r0x, gdy = goals[1] - r0y;
    float PG = (gdx * (rx - r0x) + gdy * (ry - r0y))
             / (sqrtf(gdx * gdx + gdy * gdy) + 0.001f);

    float px = out_state[4 * i], py = out_state[4 * i + 1];
    float ddx = px - rx, ddy = py - ry;
    float dist = sqrtf(ddx * ddx + ddy * ddy + 0.001f);
    float blame = (i == 0) ? 0.f
                : __builtin_amdgcn_exp2f(dist * -1.2022458675f);

    cost_out[i] = cost_in[i] + (-4.f * PG + blame);
    reinterpret_cast<float4*>(stacked_first)[i] =
        reinterpret_cast<const float4*>(stacked_in)[i];  // stacked[0:N]
}

extern "C" void kernel_launch(void* const* d_in, const int* in_sizes, int n_in,
                              void* d_out, int out_size, void* d_ws, size_t ws_size,
                              hipStream_t stream) {
    const float* state      = (const float*)d_in[0];   // (N,4)
    const float* cost       = (const float*)d_in[1];   // (N,1)
    const float* stacked_in = (const float*)d_in[2];   // (N,4)
    const float* goals      = (const float*)d_in[3];   // (N,2)
    const float* robot_init = (const float*)d_in[4];   // (2,)

    float* out          = (float*)d_out;
    float* out_state    = out;               // N*4
    float* out_cost     = out + NN * 4;      // N
    float* out_stacked  = out + NN * 5;      // 2N*4

    float2* part = (float2*)d_ws;            // NCHUNK * NN float2 = 2 MB

    dim3 gridA(NN / 256, NCHUNK);            // 16 x 64 = 1024 blocks (4/CU)
    rep_partial<<<gridA, 256, 0, stream>>>(state, part);

    propagate<<<NN / 256, 256, 0, stream>>>(state, goals, part,
                                            out_state, out_stacked + NN * 4);

    cost_and_copy<<<NN / 256, 256, 0, stream>>>(out_state, cost, goals, robot_init,
                                                stacked_in, out_cost, out_stacked);
}

// Round 3
// 69.086 us; speedup vs baseline: 1.1083x; 1.0477x over previous
//
#include <hip/hip_runtime.h>

#define NN 4096

// attr = K*(desired_speed*e_goal - vel)*mass, K=2, mass=60, speed=1.5 (all agents)
//      = 180*e_goal - 120*vel
__device__ inline float4 propagate_one(float2 pos, float2 vel, float2 goal, float2 F) {
    float tgx = goal.x - pos.x, tgy = goal.y - pos.y;
    float dist = sqrtf(tgx * tgx + tgy * tgy);
    float inv = 1.f / (dist + 1e-8f);
    float Fx = F.x + 180.f * (tgx * inv) - 120.f * vel.x;
    float Fy = F.y + 180.f * (tgy * inv) - 120.f * vel.y;
    float vnx = vel.x + Fx * (0.4f / 60.f);
    float vny = vel.y + Fy * (0.4f / 60.f);
    float sp = sqrtf(vnx * vnx + vny * vny);
    float sc = fminf(1.f, 1.5f / (sp + 1e-8f));
    vnx *= sc; vny *= sc;
    return make_float4(pos.x + vnx * 0.4f, pos.y + vny * 0.4f, vnx, vny);
}

// One dispatch does everything. Block = 16 waves; wave w owns agent
// i = blk*16 + w and sums repulsion over all 4096 j (64 j's/lane + butterfly).
// Every block ALSO recomputes the robot's (i=0) total force — wave w takes
// j in [w*256, w*256+256) — so pos_new[0] is derivable block-locally and the
// cost epilogue needs no second dispatch. Diagonal terms are exactly 0
// (dx=dy=0 -> w*dx=0), no masking.
// exp folding: 10*exp((0.6-d)/0.71) = exp2(C0E - C1E*d),
//   C1E = log2e/0.71, C0E = (0.6/0.71 + ln10)*log2e
__global__ __launch_bounds__(1024) void fused_step(
    const float* __restrict__ state, const float* __restrict__ cost_in,
    const float* __restrict__ stacked_in, const float* __restrict__ goals,
    const float* __restrict__ robot_init,
    float* __restrict__ out_state, float* __restrict__ out_cost,
    float* __restrict__ out_stacked)
{
    __shared__ float2 sp[NN];      // all positions, 32 KB
    __shared__ float2 sF[16];      // per-wave force for the block's 16 agents
    __shared__ float2 sR[16];      // per-wave partial of robot force
    __shared__ float2 sPN[16];     // pos_new for the block's 16 agents
    __shared__ float2 sRobot;      // robot pos_new

    const int tid = threadIdx.x;

    // Stage all positions (coalesced float4 loads, 4 per thread).
#pragma unroll
    for (int k = 0; k < 4; ++k) {
        int idx = tid + k * 1024;
        float4 s = reinterpret_cast<const float4*>(state)[idx];
        sp[idx] = make_float2(s.x, s.y);
    }
    __syncthreads();

    const int wave = tid >> 6, lane = tid & 63;
    const int i = blockIdx.x * 16 + wave;
    const float2 pi = sp[i];       // lane-uniform broadcast
    const float2 p0 = sp[0];

    const float C1E = 2.0319648462f;
    const float C0E = 4.5411071f;

    float fx = 0.f, fy = 0.f, rfx = 0.f, rfy = 0.f;
#pragma unroll 8
    for (int t = 0; t < 64; ++t) {
        float2 q = sp[t * 64 + lane];
        float dx = pi.x - q.x, dy = pi.y - q.y;
        float d2 = fmaf(dy, dy, fmaf(dx, dx, 1e-8f));
        float inv_d = __builtin_amdgcn_rsqf(d2);
        float e = __builtin_amdgcn_exp2f(fmaf(-C1E, d2 * inv_d, C0E));
        float w = e * inv_d;
        fx = fmaf(w, dx, fx); fy = fmaf(w, dy, fy);
    }
#pragma unroll
    for (int t = 0; t < 4; ++t) {   // this wave's slice of the robot's force
        float2 q = sp[wave * 256 + t * 64 + lane];
        float dx = p0.x - q.x, dy = p0.y - q.y;
        float d2 = fmaf(dy, dy, fmaf(dx, dx, 1e-8f));
        float inv_d = __builtin_amdgcn_rsqf(d2);
        float e = __builtin_amdgcn_exp2f(fmaf(-C1E, d2 * inv_d, C0E));
        float w = e * inv_d;
        rfx = fmaf(w, dx, rfx); rfy = fmaf(w, dy, rfy);
    }
#pragma unroll
    for (int off = 32; off > 0; off >>= 1) {   // 64-lane butterfly
        fx  += __shfl_xor(fx,  off);
        fy  += __shfl_xor(fy,  off);
        rfx += __shfl_xor(rfx, off);
        rfy += __shfl_xor(rfy, off);
    }
    if (lane == 0) { sF[wave] = make_float2(fx, fy); sR[wave] = make_float2(rfx, rfy); }
    __syncthreads();

    if (tid < 16) {                 // propagate the block's 16 agents
        int iw = blockIdx.x * 16 + tid;
        float4 s = reinterpret_cast<const float4*>(state)[iw];
        float2 g = reinterpret_cast<const float2*>(goals)[iw];
        float4 r = propagate_one(make_float2(s.x, s.y), make_float2(s.z, s.w), g, sF[tid]);
        reinterpret_cast<float4*>(out_state)[iw] = r;
        sPN[tid] = make_float2(r.x, r.y);
    } else if (tid == 31) {         // robot pose (redundant per block)
        float2 F0 = make_float2(0.f, 0.f);
#pragma unroll
        for (int c = 0; c < 16; ++c) { F0.x += sR[c].x; F0.y += sR[c].y; }
        float4 s0 = reinterpret_cast<const float4*>(state)[0];
        float2 g0 = reinterpret_cast<const float2*>(goals)[0];
        float4 r = propagate_one(make_float2(s0.x, s0.y), make_float2(s0.z, s0.w), g0, F0);
        sRobot = make_float2(r.x, r.y);
    } else if (tid >= 64 && tid < 80) {      // stacked[N:2N] = state
        int iw = blockIdx.x * 16 + (tid - 64);
        reinterpret_cast<float4*>(out_stacked)[NN + iw] =
            reinterpret_cast<const float4*>(state)[iw];
    } else if (tid >= 128 && tid < 144) {    // stacked[0:N] = stacked_in
        int iw = blockIdx.x * 16 + (tid - 128);
        reinterpret_cast<float4*>(out_stacked)[iw] =
            reinterpret_cast<const float4*>(stacked_in)[iw];
    }
    __syncthreads();

    if (tid < 16) {                 // cost epilogue (needs robot pos_new)
        int iw = blockIdx.x * 16 + tid;
        float2 rp = sRobot;
        float r0x = robot_init[0], r0y = robot_init[1];
        float gdx = goals[0] - r0x, gdy = goals[1] - r0y;
        float PG = (gdx * (rp.x - r0x) + gdy * (rp.y - r0y))
                 / (sqrtf(gdx * gdx + gdy * gdy) + 0.001f);
        float2 pn = sPN[tid];
        float ddx = pn.x - rp.x, ddy = pn.y - rp.y;
        float dist = sqrtf(ddx * ddx + ddy * ddy + 0.001f);
        float blame = (iw == 0) ? 0.f
                    : __builtin_amdgcn_exp2f(dist * -1.2022458675f); // exp(-d/1.2)
        out_cost[iw] = cost_in[iw] + (-4.f * PG + blame);
    }
}

extern "C" void kernel_launch(void* const* d_in, const int* in_sizes, int n_in,
                              void* d_out, int out_size, void* d_ws, size_t ws_size,
                              hipStream_t stream) {
    const float* state      = (const float*)d_in[0];   // (N,4)
    const float* cost       = (const float*)d_in[1];   // (N,1)
    const float* stacked_in = (const float*)d_in[2];   // (N,4)
    const float* goals      = (const float*)d_in[3];   // (N,2)
    const float* robot_init = (const float*)d_in[4];   // (2,)

    float* out         = (float*)d_out;
    float* out_state   = out;               // N*4
    float* out_cost    = out + NN * 4;      // N
    float* out_stacked = out + NN * 5;      // 2N*4

    fused_step<<<NN / 16, 1024, 0, stream>>>(state, cost, stacked_in, goals,
                                             robot_init, out_state, out_cost,
                                             out_stacked);
}